// Round 2
// baseline (831.731 us; speedup 1.0000x reference)
//
#include <hip/hip_runtime.h>
#include <math.h>

// Problem dims (fixed by reference)
#define BB   8
#define TT   2048
#define CIN  512
#define DD   1024
#define MM   (BB * TT)     // 16384 rows for the GEMMs

// K1 GEMM tiling: 128x128 block tile, 16x16 threads, 8x8x2 micro-tile
constexpr int BM = 128;
constexpr int BN = 128;
constexpr int BK = 16;

// K2 chunked scan
#define NCHUNK 16
#define CLEN   (TT / NCHUNK)   // 128
#define WARM   128             // speculative warm-up steps (see analysis)

// softplus(z) = logaddexp(z, 0) — matches jax.nn.softplus / np.logaddexp
__device__ __forceinline__ float softplus_f(float z) {
    return fmaxf(z, 0.f) + log1pf(expf(-fabsf(z)));
}

// K1: fused dual GEMM  zd = x@Wd, zb = x@Wb  (+bias)  →  a_step, b_step
__global__ __launch_bounds__(256, 2) void k1_gemm_act(
    const float* __restrict__ x,      // [MM, CIN]
    const float* __restrict__ Wd,     // [CIN, DD]
    const float* __restrict__ Wb,     // [CIN, DD]
    const float* __restrict__ bd,     // [DD]
    const float* __restrict__ bb,     // [DD]
    const float* __restrict__ A_log,  // [DD]
    float* __restrict__ a_out,        // [MM, DD]
    float* __restrict__ b_out)        // [MM, DD]
{
    // xs transposed: xs[k][m]. +4 pad keeps 16B alignment AND breaks store conflicts.
    __shared__ float xs[BK][BM + 4];
    __shared__ float wds[BK][BN];   // stride 128 floats: col reads at tx*4 → 2-way (free)
    __shared__ float wbs[BK][BN];

    const int tid = threadIdx.x;
    const int n0  = blockIdx.x * BN;
    const int m0  = blockIdx.y * BM;
    const int tx  = tid & 15;          // col group
    const int ty  = tid >> 4;          // row group

    // staging indices
    const int lm = tid >> 2;           // 0..63  (x rows lm and lm+64)
    const int lk = (tid & 3) * 4;      // 0,4,8,12
    const int wr = tid >> 4;           // 0..15  w row
    const int wc = (tid & 15) * 4;     // 0..60  w cols wc and wc+64

    float accd[8][8], accb[8][8];
#pragma unroll
    for (int r = 0; r < 8; ++r)
#pragma unroll
        for (int c = 0; c < 8; ++c) { accd[r][c] = 0.f; accb[r][c] = 0.f; }

    // ---- preload tile 0 into registers ----
    const float* xp0 = x + (size_t)(m0 + lm) * CIN + lk;
    const float* xp1 = x + (size_t)(m0 + lm + 64) * CIN + lk;
    const float* wdp = Wd + (size_t)wr * DD + n0 + wc;
    const float* wbp = Wb + (size_t)wr * DD + n0 + wc;
    float4 xv0 = *(const float4*)(xp0);
    float4 xv1 = *(const float4*)(xp1);
    float4 wd0 = *(const float4*)(wdp);
    float4 wd1 = *(const float4*)(wdp + 64);
    float4 wb0 = *(const float4*)(wbp);
    float4 wb1 = *(const float4*)(wbp + 64);

    for (int k0 = 0; k0 < CIN; k0 += BK) {
        __syncthreads();   // previous tile's compute done
        // transposed x store (2-way bank aliasing only — free)
        xs[lk + 0][lm] = xv0.x;  xs[lk + 1][lm] = xv0.y;
        xs[lk + 2][lm] = xv0.z;  xs[lk + 3][lm] = xv0.w;
        xs[lk + 0][lm + 64] = xv1.x;  xs[lk + 1][lm + 64] = xv1.y;
        xs[lk + 2][lm + 64] = xv1.z;  xs[lk + 3][lm + 64] = xv1.w;
        *(float4*)&wds[wr][wc]      = wd0;
        *(float4*)&wds[wr][wc + 64] = wd1;
        *(float4*)&wbs[wr][wc]      = wb0;
        *(float4*)&wbs[wr][wc + 64] = wb1;
        __syncthreads();

        // issue next tile's global loads (in flight during compute)
        const int kn = k0 + BK;
        if (kn < CIN) {
            xv0 = *(const float4*)(xp0 + kn);
            xv1 = *(const float4*)(xp1 + kn);
            wd0 = *(const float4*)(wdp + (size_t)kn * DD);
            wd1 = *(const float4*)(wdp + (size_t)kn * DD + 64);
            wb0 = *(const float4*)(wbp + (size_t)kn * DD);
            wb1 = *(const float4*)(wbp + (size_t)kn * DD + 64);
        }

#pragma unroll
        for (int kk = 0; kk < BK; ++kk) {
            float4 xa = *(const float4*)&xs[kk][ty * 4];
            float4 xb = *(const float4*)&xs[kk][64 + ty * 4];
            float4 d0 = *(const float4*)&wds[kk][tx * 4];
            float4 d1 = *(const float4*)&wds[kk][64 + tx * 4];
            float4 c0 = *(const float4*)&wbs[kk][tx * 4];
            float4 c1 = *(const float4*)&wbs[kk][64 + tx * 4];
            float xr[8] = {xa.x, xa.y, xa.z, xa.w, xb.x, xb.y, xb.z, xb.w};
            float wd[8] = {d0.x, d0.y, d0.z, d0.w, d1.x, d1.y, d1.z, d1.w};
            float wb[8] = {c0.x, c0.y, c0.z, c0.w, c1.x, c1.y, c1.z, c1.w};
#pragma unroll
            for (int r = 0; r < 8; ++r) {
                const float xi = xr[r];
#pragma unroll
                for (int c = 0; c < 8; ++c) {
                    accd[r][c] = fmaf(xi, wd[c], accd[r][c]);
                    accb[r][c] = fmaf(xi, wb[c], accb[r][c]);
                }
            }
        }
    }

    // ---- epilogue ----
    const int nc0 = n0 + tx * 4;
    float4 bdq[2], bbq[2], alq[2];
    bdq[0] = *(const float4*)(bd + nc0);      bdq[1] = *(const float4*)(bd + nc0 + 64);
    bbq[0] = *(const float4*)(bb + nc0);      bbq[1] = *(const float4*)(bb + nc0 + 64);
    alq[0] = *(const float4*)(A_log + nc0);   alq[1] = *(const float4*)(A_log + nc0 + 64);
    float Aq[2][4];
#pragma unroll
    for (int q = 0; q < 2; ++q) {
        Aq[q][0] = expf(alq[q].x); Aq[q][1] = expf(alq[q].y);
        Aq[q][2] = expf(alq[q].z); Aq[q][3] = expf(alq[q].w);
    }

#pragma unroll
    for (int p = 0; p < 2; ++p) {
#pragma unroll
        for (int i = 0; i < 4; ++i) {
            const int r = p * 4 + i;
            const int m = m0 + p * 64 + ty * 4 + i;
            float* ap = a_out + (size_t)m * DD + nc0;
            float* bp = b_out + (size_t)m * DD + nc0;
#pragma unroll
            for (int q = 0; q < 2; ++q) {
                const float* bdv = (const float*)&bdq[q];
                const float* bbv = (const float*)&bbq[q];
                float av[4], bv[4];
#pragma unroll
                for (int j = 0; j < 4; ++j) {
                    float zd    = accd[r][q * 4 + j] + bdv[j];
                    float delta = softplus_f(zd);
                    float zb    = accb[r][q * 4 + j] + bbv[j];
                    av[j] = expf(-delta * Aq[q][j]);
                    bv[j] = delta * zb;
                }
                *(float4*)(ap + q * 64) = make_float4(av[0], av[1], av[2], av[3]);
                *(float4*)(bp + q * 64) = make_float4(bv[0], bv[1], bv[2], bv[3]);
            }
        }
    }
}

// K2: chunked speculative spiking scan. One thread per (batch,channel,chunk).
// Warm-up of WARM steps from h=0 converges to the true state: any reset sets
// h=0 exactly (erases history); absent resets the h0-contribution decays as
// exp(-sum delta*A) ~ e^-100 over 128 steps — below fp32 rounding by >8 sigma.
__global__ __launch_bounds__(64) void k2_scan(
    const float* __restrict__ a,     // [BB, TT, DD]
    const float* __restrict__ b,     // [BB, TT, DD]
    const float* __restrict__ thr,   // [DD]
    float* __restrict__ hout,        // [BB, TT, DD]
    float* __restrict__ sout)        // [BB, TT, DD]
{
    const int gid   = blockIdx.x * 64 + threadIdx.x;   // 0..8191
    const int batch = gid >> 10;
    const int d     = gid & (DD - 1);
    const float th  = thr[d];
    const size_t base = (size_t)batch * TT * DD + d;

    const int chunk = blockIdx.y;
    const int t0    = chunk * CLEN;
    const int tw    = (chunk == 0) ? 0 : (t0 - WARM);

    const float* ap = a + base + (size_t)tw * DD;
    const float* bp = b + base + (size_t)tw * DD;

    float h = 0.f;
#pragma unroll 4
    for (int t = tw; t < t0; ++t) {            // speculative warm-up, no stores
        const float av = *ap; const float bv = *bp;
        ap += DD; bp += DD;
        h = fmaf(av, h, bv);
        h = ((h - th) > 0.f) ? 0.f : h;
    }

    float* hp = hout + base + (size_t)t0 * DD;
    float* spp = sout + base + (size_t)t0 * DD;
#pragma unroll 4
    for (int t = 0; t < CLEN; ++t) {
        const float av = *ap; const float bv = *bp;
        ap += DD; bp += DD;
        h = fmaf(av, h, bv);
        const bool spike = (h - th) > 0.f;
        *spp = spike ? 1.f : 0.f;
        h = spike ? 0.f : h;
        *hp = h;
        hp += DD; spp += DD;
    }
}

// K3: in-place LayerNorm over last dim (D=1024), one block per row.
__global__ __launch_bounds__(256) void k3_ln(
    float* __restrict__ h,           // [MM, DD] in/out
    const float* __restrict__ gamma,
    const float* __restrict__ beta)
{
    const int row = blockIdx.x;
    const int tid = threadIdx.x;
    const int lane = tid & 63;
    const int wid  = tid >> 6;

    __shared__ float red[4];
    __shared__ float bc[2];

    float* rp = h + (size_t)row * DD + tid * 4;
    float4 v = *(const float4*)rp;

    float s = v.x + v.y + v.z + v.w;
#pragma unroll
    for (int off = 32; off > 0; off >>= 1) s += __shfl_down(s, off);
    if (lane == 0) red[wid] = s;
    __syncthreads();
    if (tid == 0) bc[0] = (red[0] + red[1] + red[2] + red[3]) * (1.0f / DD);
    __syncthreads();
    const float mu = bc[0];

    float dx = v.x - mu, dy = v.y - mu, dz = v.z - mu, dw = v.w - mu;
    float ss = dx * dx + dy * dy + dz * dz + dw * dw;
#pragma unroll
    for (int off = 32; off > 0; off >>= 1) ss += __shfl_down(ss, off);
    __syncthreads();
    if (lane == 0) red[wid] = ss;
    __syncthreads();
    if (tid == 0) bc[1] = (red[0] + red[1] + red[2] + red[3]) * (1.0f / DD);
    __syncthreads();
    const float inv = 1.0f / sqrtf(bc[1] + 1e-5f);

    float4 g  = *(const float4*)(gamma + tid * 4);
    float4 be = *(const float4*)(beta + tid * 4);
    float4 o;
    o.x = dx * inv * g.x + be.x;
    o.y = dy * inv * g.y + be.y;
    o.z = dz * inv * g.z + be.z;
    o.w = dw * inv * g.w + be.w;
    *(float4*)rp = o;
}

extern "C" void kernel_launch(void* const* d_in, const int* in_sizes, int n_in,
                              void* d_out, int out_size, void* d_ws, size_t ws_size,
                              hipStream_t stream) {
    const float* x     = (const float*)d_in[0];
    const float* Wd    = (const float*)d_in[1];
    const float* bd    = (const float*)d_in[2];
    const float* Wb    = (const float*)d_in[3];
    const float* bb    = (const float*)d_in[4];
    const float* A_log = (const float*)d_in[5];
    const float* thr   = (const float*)d_in[6];
    const float* gamma = (const float*)d_in[7];
    const float* beta  = (const float*)d_in[8];

    float* out    = (float*)d_out;                    // [MM, DD] LN output
    float* spikes = out + (size_t)MM * DD;            // [MM, DD]
    float* a_ws   = (float*)d_ws;                     // [MM, DD]
    float* b_ws   = a_ws + (size_t)MM * DD;           // [MM, DD]

    dim3 g1(DD / BN, MM / BM);                        // (8, 128)
    k1_gemm_act<<<g1, 256, 0, stream>>>(x, Wd, Wb, bd, bb, A_log, a_ws, b_ws);

    dim3 g2(BB * DD / 64, NCHUNK);                    // (128, 16)
    k2_scan<<<g2, 64, 0, stream>>>(a_ws, b_ws, thr, out, spikes);

    k3_ln<<<MM, 256, 0, stream>>>(out, gamma, beta);
}

// Round 3
// 692.552 us; speedup vs baseline: 1.2010x; 1.2010x over previous
//
#include <hip/hip_runtime.h>
#include <math.h>

// Problem dims (fixed by reference)
#define BB   8
#define TT   2048
#define CIN  512
#define DD   1024
#define MM   (BB * TT)     // 16384 rows for the GEMMs

// K1 GEMM tiling: 64x128 block tile, 256 threads, 4x8 dual micro-tile.
// NOTE: 8x8 dual micro-tile (128 accs) spilled to scratch in round 2
// (WRITE_SIZE 131MB -> 1.34GB). Keep accumulator count at 64.
constexpr int BM = 64;
constexpr int BN = 128;
constexpr int BK = 16;

// K2 chunked scan: 32 chunks x 64 steps, 128-step speculative warm-up.
#define NCHUNK 32
#define CLEN   (TT / NCHUNK)   // 64
#define WARM   128

// softplus(z) = logaddexp(z, 0) — matches jax.nn.softplus / np.logaddexp
__device__ __forceinline__ float softplus_f(float z) {
    return fmaxf(z, 0.f) + log1pf(expf(-fabsf(z)));
}

// K1: fused dual GEMM  zd = x@Wd, zb = x@Wb  (+bias)  →  a_step, b_step
__global__ __launch_bounds__(256) void k1_gemm_act(
    const float* __restrict__ x,      // [MM, CIN]
    const float* __restrict__ Wd,     // [CIN, DD]
    const float* __restrict__ Wb,     // [CIN, DD]
    const float* __restrict__ bd,     // [DD]
    const float* __restrict__ bb,     // [DD]
    const float* __restrict__ A_log,  // [DD]
    float* __restrict__ a_out,        // [MM, DD]
    float* __restrict__ b_out)        // [MM, DD]
{
    // xs transposed: xs[k][m] -> x-fragments are b128 reads, stores 2-way (free).
    __shared__ float xs[BK][BM + 4];
    __shared__ float wds[BK][BN];   // col reads at tx*4 / tx*4+64: 2-way (free)
    __shared__ float wbs[BK][BN];

    const int tid = threadIdx.x;
    const int n0  = blockIdx.x * BN;
    const int m0  = blockIdx.y * BM;
    const int tx  = tid & 15;          // col group
    const int ty  = tid >> 4;          // row group

    // staging indices
    const int lm = tid >> 2;           // 0..63   x row
    const int lk = (tid & 3) * 4;      // 0,4,8,12
    const int wr = tid >> 4;           // 0..15   w row
    const int wc = (tid & 15) * 4;     // 0..60   w cols wc and wc+64

    float accd[4][8], accb[4][8];
#pragma unroll
    for (int r = 0; r < 4; ++r)
#pragma unroll
        for (int c = 0; c < 8; ++c) { accd[r][c] = 0.f; accb[r][c] = 0.f; }

    // ---- preload tile 0 into registers ----
    const float* xp  = x + (size_t)(m0 + lm) * CIN + lk;
    const float* wdp = Wd + (size_t)wr * DD + n0 + wc;
    const float* wbp = Wb + (size_t)wr * DD + n0 + wc;
    float4 xv  = *(const float4*)(xp);
    float4 wd0 = *(const float4*)(wdp);
    float4 wd1 = *(const float4*)(wdp + 64);
    float4 wb0 = *(const float4*)(wbp);
    float4 wb1 = *(const float4*)(wbp + 64);

    for (int k0 = 0; k0 < CIN; k0 += BK) {
        __syncthreads();   // previous tile's compute done
        xs[lk + 0][lm] = xv.x;  xs[lk + 1][lm] = xv.y;
        xs[lk + 2][lm] = xv.z;  xs[lk + 3][lm] = xv.w;
        *(float4*)&wds[wr][wc]      = wd0;
        *(float4*)&wds[wr][wc + 64] = wd1;
        *(float4*)&wbs[wr][wc]      = wb0;
        *(float4*)&wbs[wr][wc + 64] = wb1;
        __syncthreads();

        // issue next tile's global loads (in flight during compute)
        const int kn = k0 + BK;
        if (kn < CIN) {
            xv  = *(const float4*)(xp + kn);
            wd0 = *(const float4*)(wdp + (size_t)kn * DD);
            wd1 = *(const float4*)(wdp + (size_t)kn * DD + 64);
            wb0 = *(const float4*)(wbp + (size_t)kn * DD);
            wb1 = *(const float4*)(wbp + (size_t)kn * DD + 64);
        }

#pragma unroll
        for (int kk = 0; kk < BK; ++kk) {
            float4 xa = *(const float4*)&xs[kk][ty * 4];
            float4 d0 = *(const float4*)&wds[kk][tx * 4];
            float4 d1 = *(const float4*)&wds[kk][64 + tx * 4];
            float4 c0 = *(const float4*)&wbs[kk][tx * 4];
            float4 c1 = *(const float4*)&wbs[kk][64 + tx * 4];
            float xr[4] = {xa.x, xa.y, xa.z, xa.w};
            float wd[8] = {d0.x, d0.y, d0.z, d0.w, d1.x, d1.y, d1.z, d1.w};
            float wb[8] = {c0.x, c0.y, c0.z, c0.w, c1.x, c1.y, c1.z, c1.w};
#pragma unroll
            for (int r = 0; r < 4; ++r) {
                const float xi = xr[r];
#pragma unroll
                for (int c = 0; c < 8; ++c) {
                    accd[r][c] = fmaf(xi, wd[c], accd[r][c]);
                    accb[r][c] = fmaf(xi, wb[c], accb[r][c]);
                }
            }
        }
    }

    // ---- epilogue ----
    const int nc0 = n0 + tx * 4;
    float4 bdq[2], bbq[2], alq[2];
    bdq[0] = *(const float4*)(bd + nc0);      bdq[1] = *(const float4*)(bd + nc0 + 64);
    bbq[0] = *(const float4*)(bb + nc0);      bbq[1] = *(const float4*)(bb + nc0 + 64);
    alq[0] = *(const float4*)(A_log + nc0);   alq[1] = *(const float4*)(A_log + nc0 + 64);
    float Aq[2][4];
#pragma unroll
    for (int q = 0; q < 2; ++q) {
        Aq[q][0] = expf(alq[q].x); Aq[q][1] = expf(alq[q].y);
        Aq[q][2] = expf(alq[q].z); Aq[q][3] = expf(alq[q].w);
    }

#pragma unroll
    for (int r = 0; r < 4; ++r) {
        const int m = m0 + ty * 4 + r;
        float* ap = a_out + (size_t)m * DD + nc0;
        float* bp = b_out + (size_t)m * DD + nc0;
#pragma unroll
        for (int q = 0; q < 2; ++q) {
            const float* bdv = (const float*)&bdq[q];
            const float* bbv = (const float*)&bbq[q];
            float av[4], bv[4];
#pragma unroll
            for (int j = 0; j < 4; ++j) {
                float zd    = accd[r][q * 4 + j] + bdv[j];
                float delta = softplus_f(zd);
                float zb    = accb[r][q * 4 + j] + bbv[j];
                av[j] = expf(-delta * Aq[q][j]);
                bv[j] = delta * zb;
            }
            *(float4*)(ap + q * 64) = make_float4(av[0], av[1], av[2], av[3]);
            *(float4*)(bp + q * 64) = make_float4(bv[0], bv[1], bv[2], bv[3]);
        }
    }
}

// K2: chunked speculative spiking scan. One thread per (batch,channel,chunk).
// Warm-up from h=0 converges to the true state: any reset sets h=0 exactly
// (erases history); absent resets the h0-contribution decays as
// exp(-sum delta*A) <= e^-90 over 128 steps even for A=1 — far below fp32
// rounding. Chunk 1's warm-up clamps to t=0 (exact prefix).
__global__ __launch_bounds__(64) void k2_scan(
    const float* __restrict__ a,     // [BB, TT, DD]
    const float* __restrict__ b,     // [BB, TT, DD]
    const float* __restrict__ thr,   // [DD]
    float* __restrict__ hout,        // [BB, TT, DD]
    float* __restrict__ sout)        // [BB, TT, DD]
{
    const int gid   = blockIdx.x * 64 + threadIdx.x;   // 0..8191
    const int batch = gid >> 10;
    const int d     = gid & (DD - 1);
    const float th  = thr[d];
    const size_t base = (size_t)batch * TT * DD + d;

    const int chunk = blockIdx.y;
    const int t0    = chunk * CLEN;
    const int tw    = (t0 - WARM > 0) ? (t0 - WARM) : 0;

    const float* ap = a + base + (size_t)tw * DD;
    const float* bp = b + base + (size_t)tw * DD;

    float h = 0.f;
    for (int t = tw; t < t0; ++t) {            // speculative warm-up, no stores
        const float av = *ap; const float bv = *bp;
        ap += DD; bp += DD;
        h = fmaf(av, h, bv);
        h = ((h - th) > 0.f) ? 0.f : h;
    }

    float* hp  = hout + base + (size_t)t0 * DD;
    float* spp = sout + base + (size_t)t0 * DD;
#pragma unroll 8
    for (int t = 0; t < CLEN; ++t) {
        const float av = *ap; const float bv = *bp;
        ap += DD; bp += DD;
        h = fmaf(av, h, bv);
        const bool spike = (h - th) > 0.f;
        *spp = spike ? 1.f : 0.f;
        h = spike ? 0.f : h;
        *hp = h;
        hp += DD; spp += DD;
    }
}

// K3: in-place LayerNorm over last dim (D=1024), one block per row.
__global__ __launch_bounds__(256) void k3_ln(
    float* __restrict__ h,           // [MM, DD] in/out
    const float* __restrict__ gamma,
    const float* __restrict__ beta)
{
    const int row = blockIdx.x;
    const int tid = threadIdx.x;
    const int lane = tid & 63;
    const int wid  = tid >> 6;

    __shared__ float red[4];
    __shared__ float bc[2];

    float* rp = h + (size_t)row * DD + tid * 4;
    float4 v = *(const float4*)rp;

    float s = v.x + v.y + v.z + v.w;
#pragma unroll
    for (int off = 32; off > 0; off >>= 1) s += __shfl_down(s, off);
    if (lane == 0) red[wid] = s;
    __syncthreads();
    if (tid == 0) bc[0] = (red[0] + red[1] + red[2] + red[3]) * (1.0f / DD);
    __syncthreads();
    const float mu = bc[0];

    float dx = v.x - mu, dy = v.y - mu, dz = v.z - mu, dw = v.w - mu;
    float ss = dx * dx + dy * dy + dz * dz + dw * dw;
#pragma unroll
    for (int off = 32; off > 0; off >>= 1) ss += __shfl_down(ss, off);
    __syncthreads();
    if (lane == 0) red[wid] = ss;
    __syncthreads();
    if (tid == 0) bc[1] = (red[0] + red[1] + red[2] + red[3]) * (1.0f / DD);
    __syncthreads();
    const float inv = 1.0f / sqrtf(bc[1] + 1e-5f);

    float4 g  = *(const float4*)(gamma + tid * 4);
    float4 be = *(const float4*)(beta + tid * 4);
    float4 o;
    o.x = dx * inv * g.x + be.x;
    o.y = dy * inv * g.y + be.y;
    o.z = dz * inv * g.z + be.z;
    o.w = dw * inv * g.w + be.w;
    *(float4*)rp = o;
}

extern "C" void kernel_launch(void* const* d_in, const int* in_sizes, int n_in,
                              void* d_out, int out_size, void* d_ws, size_t ws_size,
                              hipStream_t stream) {
    const float* x     = (const float*)d_in[0];
    const float* Wd    = (const float*)d_in[1];
    const float* bd    = (const float*)d_in[2];
    const float* Wb    = (const float*)d_in[3];
    const float* bb    = (const float*)d_in[4];
    const float* A_log = (const float*)d_in[5];
    const float* thr   = (const float*)d_in[6];
    const float* gamma = (const float*)d_in[7];
    const float* beta  = (const float*)d_in[8];

    float* out    = (float*)d_out;                    // [MM, DD] LN output
    float* spikes = out + (size_t)MM * DD;            // [MM, DD]
    float* a_ws   = (float*)d_ws;                     // [MM, DD]
    float* b_ws   = a_ws + (size_t)MM * DD;           // [MM, DD]

    dim3 g1(DD / BN, MM / BM);                        // (8, 256)
    k1_gemm_act<<<g1, 256, 0, stream>>>(x, Wd, Wb, bd, bb, A_log, a_ws, b_ws);

    dim3 g2(BB * DD / 64, NCHUNK);                    // (128, 32)
    k2_scan<<<g2, 64, 0, stream>>>(a_ws, b_ws, thr, out, spikes);

    k3_ln<<<MM, 256, 0, stream>>>(out, gamma, beta);
}

// Round 4
// 684.223 us; speedup vs baseline: 1.2156x; 1.0122x over previous
//
#include <hip/hip_runtime.h>
#include <math.h>

// Problem dims (fixed by reference)
#define BB   8
#define TT   2048
#define CIN  512
#define DD   1024
#define MM   (BB * TT)     // 16384 rows for the GEMMs

// K1 GEMM tiling: 128x64 block tile, 256 threads, 8x4 dual micro-tile.
// bytes/FMA = 2/c + 4/r = 1.0 (vs 1.25 for 4x8) at the same 64 accumulators.
// NOTE: 128-acc variants spilled in round 2 (WRITE_SIZE 131MB->1.34GB). Keep 64.
constexpr int BM = 128;
constexpr int BN = 64;
constexpr int BK = 16;

// K2 chunked scan: 16 chunks x 128 steps, 128-step speculative warm-up,
// explicit double-buffered register prefetch (PF-step batches).
#define NCHUNK 16
#define CLEN   (TT / NCHUNK)   // 128
#define WARM   128
#define PF     16

// softplus(z) = logaddexp(z, 0) — matches jax.nn.softplus / np.logaddexp
__device__ __forceinline__ float softplus_f(float z) {
    return fmaxf(z, 0.f) + log1pf(expf(-fabsf(z)));
}

// K1: fused dual GEMM  zd = x@Wd, zb = x@Wb  (+bias)  →  a_step, b_step
__global__ __launch_bounds__(256) void k1_gemm_act(
    const float* __restrict__ x,      // [MM, CIN]
    const float* __restrict__ Wd,     // [CIN, DD]
    const float* __restrict__ Wb,     // [CIN, DD]
    const float* __restrict__ bd,     // [DD]
    const float* __restrict__ bb,     // [DD]
    const float* __restrict__ A_log,  // [DD]
    float* __restrict__ a_out,        // [MM, DD]
    float* __restrict__ b_out)        // [MM, DD]
{
    // xs transposed: xs[k][m] -> x-fragments are b128 reads; scatter stores 2-way (free).
    __shared__ float xs[BK][BM + 4];
    __shared__ float wds[BK][BN];
    __shared__ float wbs[BK][BN];

    const int tid = threadIdx.x;
    const int n0  = blockIdx.x * BN;
    const int m0  = blockIdx.y * BM;
    const int tx  = tid & 15;          // col group: 4 cols each
    const int ty  = tid >> 4;          // row group: 8 rows each

    // staging indices
    const int lm = tid >> 1;           // 0..127  x row
    const int lk = (tid & 1) * 8;      // 0 or 8  (two float4 = 8 k)
    const int wr = tid >> 4;           // 0..15   w row
    const int wc = (tid & 15) * 4;     // 0..60   w col

    float accd[8][4], accb[8][4];
#pragma unroll
    for (int r = 0; r < 8; ++r)
#pragma unroll
        for (int c = 0; c < 4; ++c) { accd[r][c] = 0.f; accb[r][c] = 0.f; }

    // ---- preload tile 0 into registers ----
    const float* xp  = x + (size_t)(m0 + lm) * CIN + lk;
    const float* wdp = Wd + (size_t)wr * DD + n0 + wc;
    const float* wbp = Wb + (size_t)wr * DD + n0 + wc;
    float4 xva = *(const float4*)(xp);
    float4 xvb = *(const float4*)(xp + 4);
    float4 wd0 = *(const float4*)(wdp);
    float4 wb0 = *(const float4*)(wbp);

    for (int k0 = 0; k0 < CIN; k0 += BK) {
        __syncthreads();   // previous tile's compute done
        xs[lk + 0][lm] = xva.x;  xs[lk + 1][lm] = xva.y;
        xs[lk + 2][lm] = xva.z;  xs[lk + 3][lm] = xva.w;
        xs[lk + 4][lm] = xvb.x;  xs[lk + 5][lm] = xvb.y;
        xs[lk + 6][lm] = xvb.z;  xs[lk + 7][lm] = xvb.w;
        *(float4*)&wds[wr][wc] = wd0;
        *(float4*)&wbs[wr][wc] = wb0;
        __syncthreads();

        // issue next tile's global loads (in flight during compute)
        const int kn = k0 + BK;
        if (kn < CIN) {
            xva = *(const float4*)(xp + kn);
            xvb = *(const float4*)(xp + kn + 4);
            wd0 = *(const float4*)(wdp + (size_t)kn * DD);
            wb0 = *(const float4*)(wbp + (size_t)kn * DD);
        }

#pragma unroll
        for (int kk = 0; kk < BK; ++kk) {
            float4 xa  = *(const float4*)&xs[kk][ty * 8];
            float4 xa2 = *(const float4*)&xs[kk][ty * 8 + 4];
            float4 d0  = *(const float4*)&wds[kk][tx * 4];
            float4 c0  = *(const float4*)&wbs[kk][tx * 4];
            float xr[8] = {xa.x, xa.y, xa.z, xa.w, xa2.x, xa2.y, xa2.z, xa2.w};
            float wd[4] = {d0.x, d0.y, d0.z, d0.w};
            float wb[4] = {c0.x, c0.y, c0.z, c0.w};
#pragma unroll
            for (int r = 0; r < 8; ++r) {
                const float xi = xr[r];
#pragma unroll
                for (int c = 0; c < 4; ++c) {
                    accd[r][c] = fmaf(xi, wd[c], accd[r][c]);
                    accb[r][c] = fmaf(xi, wb[c], accb[r][c]);
                }
            }
        }
    }

    // ---- epilogue ----
    const int nc0 = n0 + tx * 4;
    float4 bdq = *(const float4*)(bd + nc0);
    float4 bbq = *(const float4*)(bb + nc0);
    float4 alq = *(const float4*)(A_log + nc0);
    const float* bdv = (const float*)&bdq;
    const float* bbv = (const float*)&bbq;
    float Aq[4] = {expf(alq.x), expf(alq.y), expf(alq.z), expf(alq.w)};

#pragma unroll
    for (int r = 0; r < 8; ++r) {
        const int m = m0 + ty * 8 + r;
        float av[4], bv[4];
#pragma unroll
        for (int j = 0; j < 4; ++j) {
            float zd    = accd[r][j] + bdv[j];
            float delta = softplus_f(zd);
            float zb    = accb[r][j] + bbv[j];
            av[j] = expf(-delta * Aq[j]);
            bv[j] = delta * zb;
        }
        *(float4*)(a_out + (size_t)m * DD + nc0) = make_float4(av[0], av[1], av[2], av[3]);
        *(float4*)(b_out + (size_t)m * DD + nc0) = make_float4(bv[0], bv[1], bv[2], bv[3]);
    }
}

// K2: chunked speculative spiking scan with explicit register double-buffering.
// Warm-up from h=0 converges to the true state: any reset sets h=0 exactly
// (erases history); absent resets the h0-contribution decays as
// exp(-sum delta*A) <= e^-90 over 128 steps even for A=1 — far below fp32
// rounding. Chunk 0 has no warm-up (exact prefix).
__global__ __launch_bounds__(64) void k2_scan(
    const float* __restrict__ a,     // [BB, TT, DD]
    const float* __restrict__ b,     // [BB, TT, DD]
    const float* __restrict__ thr,   // [DD]
    float* __restrict__ hout,        // [BB, TT, DD]
    float* __restrict__ sout)        // [BB, TT, DD]
{
    const int gid   = blockIdx.x * 64 + threadIdx.x;   // 0..8191
    const int batch = gid >> 10;
    const int d     = gid & (DD - 1);
    const float th  = thr[d];
    const size_t base = (size_t)batch * TT * DD + d;

    const int chunk = blockIdx.y;
    const int t0    = chunk * CLEN;
    const int nwarm = (chunk == 0) ? 0 : WARM;         // 0 or 128 steps
    const int tw    = t0 - nwarm;
    const int nwb   = nwarm / PF;                      // warm batches: 0 or 8
    const int ntot  = nwb + CLEN / PF;                 // total batches: 8 or 16 (even)

    const float* ap = a + base + (size_t)tw * DD;
    const float* bp = b + base + (size_t)tw * DD;
    float* hp = hout + base + (size_t)t0 * DD;
    float* sp = sout + base + (size_t)t0 * DD;

    float a0[PF], b0[PF], a1[PF], b1[PF];
#pragma unroll
    for (int j = 0; j < PF; ++j) { a0[j] = ap[(size_t)j * DD]; b0[j] = bp[(size_t)j * DD]; }
    ap += (size_t)PF * DD; bp += (size_t)PF * DD;

    float h = 0.f;
    for (int i = 0; i < ntot; i += 2) {
        // prefetch batch i+1 (ntot even => always valid)
#pragma unroll
        for (int j = 0; j < PF; ++j) { a1[j] = ap[(size_t)j * DD]; b1[j] = bp[(size_t)j * DD]; }
        ap += (size_t)PF * DD; bp += (size_t)PF * DD;

        // compute batch i
        if (i >= nwb) {
#pragma unroll
            for (int j = 0; j < PF; ++j) {
                h = fmaf(a0[j], h, b0[j]);
                const bool spike = (h - th) > 0.f;
                *sp = spike ? 1.f : 0.f;
                h = spike ? 0.f : h;
                *hp = h;
                hp += DD; sp += DD;
            }
        } else {
#pragma unroll
            for (int j = 0; j < PF; ++j) {
                h = fmaf(a0[j], h, b0[j]);
                h = ((h - th) > 0.f) ? 0.f : h;
            }
        }

        // prefetch batch i+2
        if (i + 2 < ntot) {
#pragma unroll
            for (int j = 0; j < PF; ++j) { a0[j] = ap[(size_t)j * DD]; b0[j] = bp[(size_t)j * DD]; }
            ap += (size_t)PF * DD; bp += (size_t)PF * DD;
        }

        // compute batch i+1
        if (i + 1 >= nwb) {
#pragma unroll
            for (int j = 0; j < PF; ++j) {
                h = fmaf(a1[j], h, b1[j]);
                const bool spike = (h - th) > 0.f;
                *sp = spike ? 1.f : 0.f;
                h = spike ? 0.f : h;
                *hp = h;
                hp += DD; sp += DD;
            }
        } else {
#pragma unroll
            for (int j = 0; j < PF; ++j) {
                h = fmaf(a1[j], h, b1[j]);
                h = ((h - th) > 0.f) ? 0.f : h;
            }
        }
    }
}

// K3: in-place LayerNorm over last dim (D=1024), one block per row.
__global__ __launch_bounds__(256) void k3_ln(
    float* __restrict__ h,           // [MM, DD] in/out
    const float* __restrict__ gamma,
    const float* __restrict__ beta)
{
    const int row = blockIdx.x;
    const int tid = threadIdx.x;
    const int lane = tid & 63;
    const int wid  = tid >> 6;

    __shared__ float red[4];
    __shared__ float bc[2];

    float* rp = h + (size_t)row * DD + tid * 4;
    float4 v = *(const float4*)rp;

    float s = v.x + v.y + v.z + v.w;
#pragma unroll
    for (int off = 32; off > 0; off >>= 1) s += __shfl_down(s, off);
    if (lane == 0) red[wid] = s;
    __syncthreads();
    if (tid == 0) bc[0] = (red[0] + red[1] + red[2] + red[3]) * (1.0f / DD);
    __syncthreads();
    const float mu = bc[0];

    float dx = v.x - mu, dy = v.y - mu, dz = v.z - mu, dw = v.w - mu;
    float ss = dx * dx + dy * dy + dz * dz + dw * dw;
#pragma unroll
    for (int off = 32; off > 0; off >>= 1) ss += __shfl_down(ss, off);
    __syncthreads();
    if (lane == 0) red[wid] = ss;
    __syncthreads();
    if (tid == 0) bc[1] = (red[0] + red[1] + red[2] + red[3]) * (1.0f / DD);
    __syncthreads();
    const float inv = 1.0f / sqrtf(bc[1] + 1e-5f);

    float4 g  = *(const float4*)(gamma + tid * 4);
    float4 be = *(const float4*)(beta + tid * 4);
    float4 o;
    o.x = dx * inv * g.x + be.x;
    o.y = dy * inv * g.y + be.y;
    o.z = dz * inv * g.z + be.z;
    o.w = dw * inv * g.w + be.w;
    *(float4*)rp = o;
}

extern "C" void kernel_launch(void* const* d_in, const int* in_sizes, int n_in,
                              void* d_out, int out_size, void* d_ws, size_t ws_size,
                              hipStream_t stream) {
    const float* x     = (const float*)d_in[0];
    const float* Wd    = (const float*)d_in[1];
    const float* bd    = (const float*)d_in[2];
    const float* Wb    = (const float*)d_in[3];
    const float* bb    = (const float*)d_in[4];
    const float* A_log = (const float*)d_in[5];
    const float* thr   = (const float*)d_in[6];
    const float* gamma = (const float*)d_in[7];
    const float* beta  = (const float*)d_in[8];

    float* out    = (float*)d_out;                    // [MM, DD] LN output
    float* spikes = out + (size_t)MM * DD;            // [MM, DD]
    float* a_ws   = (float*)d_ws;                     // [MM, DD]
    float* b_ws   = a_ws + (size_t)MM * DD;           // [MM, DD]

    dim3 g1(DD / BN, MM / BM);                        // (16, 128)
    k1_gemm_act<<<g1, 256, 0, stream>>>(x, Wd, Wb, bd, bb, A_log, a_ws, b_ws);

    dim3 g2(BB * DD / 64, NCHUNK);                    // (128, 16)
    k2_scan<<<g2, 64, 0, stream>>>(a_ws, b_ws, thr, out, spikes);

    k3_ln<<<MM, 256, 0, stream>>>(out, gamma, beta);
}